// Round 6
// baseline (172.138 us; speedup 1.0000x reference)
//
#include <hip/hip_runtime.h>

// FCOS loss, 5 FPN levels, B=16, C=80.
// Level pixel counts: 12800, 3200, 800, 208, 56 -> total 17064 (4266 quads).
// Two-stage deterministic reduction (no global atomics — R2/R3: same-line
// atomicAdds serialize to ~120us). R6: conf slices are pure branch-free
// neg_term streams (no cls/pos loads); the positive-class correction and box
// losses both live in the z==8 slice, which reloads the single conf scalar at
// (clsv, pixel) for the ~5% positive pixels.

namespace {
constexpr int NQUAD  = 4266;   // 17064 / 4
constexpr int C_     = 80;
constexpr int CCHUNK = 10;     // channels per conf block (8 chunks)
constexpr int GX     = 17;     // ceil(NQUAD/256)
constexpr float LN2  = 0.6931471805599453f;
constexpr float KNEG = -0.75f * LN2;   // -(1-alpha)*ln2
constexpr float KPOS = -0.25f * LN2;   // -alpha*ln2

struct LevelPtrs {
    const float* conf[5];
    const float* loc[5];
    const float* center[5];
    const float* ltrb[5];
    const int*   cls[5];
    const int*   pos[5];
};
}  // namespace

__device__ __forceinline__ float flog2(float x) { return __builtin_amdgcn_logf(x); }

__device__ __forceinline__ float neg_term(float v) {
    float p = fminf(fmaxf(v, 1e-8f), 0.99999999f);
    return KNEG * p * p * flog2(1.f - p);           // = -(0.75) p^2 ln(1-p)
}
__device__ __forceinline__ float pos_term(float v) {
    float p = fminf(fmaxf(v, 1e-8f), 0.99999999f);
    float om = 1.f - p;
    return KPOS * om * om * flog2(p);               // = -(0.25)(1-p)^2 ln(p)
}

__device__ __forceinline__ void level_of(int q, int& l, int& p, int& HW) {
    if (q < 3200)      { l = 0; p = 4 * q;          HW = 12800; }
    else if (q < 4000) { l = 1; p = 4 * (q - 3200); HW = 3200; }
    else if (q < 4200) { l = 2; p = 4 * (q - 4000); HW = 800; }
    else if (q < 4252) { l = 3; p = 4 * (q - 4200); HW = 208; }
    else               { l = 4; p = 4 * (q - 4252); HW = 56; }
}

// d_ws layout (floats):
//   pc  [16][8][17]  conf partial per (b, z, x)   : 2176
//   pl  [16][17]     iou partial per (b, x)       : 272
//   pcen[16][17]     centerness partial           : 272
//   pcor[16][17]     pos-correction partial       : 272
//   pn  [16][17]     pos-count partial (int)      : 272
__global__ __launch_bounds__(256) void fcos_main(LevelPtrs P,
                                                 float* __restrict__ pc,
                                                 float* __restrict__ pl,
                                                 float* __restrict__ pcen,
                                                 float* __restrict__ pcor,
                                                 int* __restrict__ pn) {
    const int b = blockIdx.y;
    const int z = blockIdx.z;           // 0..7 conf chunks, 8 = box + correction
    const int q = blockIdx.x * 256 + threadIdx.x;

    float s_conf = 0.f, s_l = 0.f, s_c = 0.f;
    int s_n = 0;
    const bool is_box = (z == 8);

    if (q < NQUAD) {
        int l, p, HW;
        level_of(q, l, p, HW);
        const size_t bHW = (size_t)b * HW;

        if (!is_box) {
            // ---- pure branch-free focal negative stream over this chunk ----
            const int c0 = z * CCHUNK;
            const float* confp = P.conf[l] + ((size_t)b * C_ + c0) * HW + p;

            float4 vb[CCHUNK];
#pragma unroll
            for (int cc = 0; cc < CCHUNK; ++cc)
                vb[cc] = *(const float4*)(confp + (size_t)cc * HW);

            float4 sc = make_float4(0.f, 0.f, 0.f, 0.f);
#pragma unroll
            for (int cc = 0; cc < CCHUNK; ++cc) {
                sc.x += neg_term(vb[cc].x);
                sc.y += neg_term(vb[cc].y);
                sc.z += neg_term(vb[cc].z);
                sc.w += neg_term(vb[cc].w);
            }
            s_conf = (sc.x + sc.y) + (sc.z + sc.w);
        } else {
            // ---- box losses + positive-class conf correction ----
            const int4 cls4 = *(const int4*)(P.cls[l] + bHW + p);
            const int4 pos4 = *(const int4*)(P.pos[l] + bHW + p);
            const int clsA[4] = {cls4.x, cls4.y, cls4.z, cls4.w};
            const int posA[4] = {pos4.x, pos4.y, pos4.z, pos4.w};
            const bool any = (posA[0] == 0) | (posA[1] == 0) |
                             (posA[2] == 0) | (posA[3] == 0);
            if (any) {
                const float* locp = P.loc[l]  + (size_t)b * 4 * HW + p;
                const float* ltrp = P.ltrb[l] + (size_t)b * 4 * HW + p;
                float la[4], ta[4], ra[4], ba[4];
                float La[4], Ta[4], Ra[4], Ba[4];
                float ca[4];
                *(float4*)la = *(const float4*)(locp);
                *(float4*)ta = *(const float4*)(locp + HW);
                *(float4*)ra = *(const float4*)(locp + 2 * HW);
                *(float4*)ba = *(const float4*)(locp + 3 * HW);
                *(float4*)La = *(const float4*)(ltrp);
                *(float4*)Ta = *(const float4*)(ltrp + HW);
                *(float4*)Ra = *(const float4*)(ltrp + 2 * HW);
                *(float4*)Ba = *(const float4*)(ltrp + 3 * HW);
                *(float4*)ca = *(const float4*)(P.center[l] + bHW + p);
#pragma unroll
                for (int i = 0; i < 4; ++i) {
                    if (posA[i] != 0) continue;
                    // focal correction at the labeled class
                    float v = P.conf[l][((size_t)b * C_ + clsA[i]) * HW + p + i];
                    s_conf += pos_term(v) - neg_term(v);

                    float lp = la[i] * 32.f, tp = ta[i] * 32.f,
                          rp = ra[i] * 32.f, bp = ba[i] * 32.f;
                    float lt = La[i] * 32.f, tt = Ta[i] * 32.f,
                          rt = Ra[i] * 32.f, bt = Ba[i] * 32.f;

                    float iw = fmaxf(fminf(lp, lt) + fminf(rp, rt), 0.f);
                    float ih = fmaxf(fminf(tp, tt) + fminf(bp, bt), 0.f);
                    float inter  = iw * ih;
                    float area_p = fmaxf(lp + rp, 0.f) * fmaxf(tp + bp, 0.f);
                    float area_t = (lt + rt) * (tt + bt);
                    float iou = inter / (area_p + area_t - inter + 1e-6f);
                    s_l += -LN2 * flog2(iou + 1e-6f);

                    float ctr = sqrtf((fminf(lt, rt) / (fmaxf(lt, rt) + 1e-6f)) *
                                      (fminf(tt, bt) / (fmaxf(tt, bt) + 1e-6f)));
                    float cp = fminf(fmaxf(ca[i], 1e-8f), 1.f - 1e-8f);
                    s_c += -LN2 * (ctr * flog2(cp) + (1.f - ctr) * flog2(1.f - cp));
                    s_n += 1;
                }
            }
        }
    }

    // wave64 shuffle reduction
    for (int o = 32; o > 0; o >>= 1) s_conf += __shfl_down(s_conf, o, 64);
    if (is_box) {
        for (int o = 32; o > 0; o >>= 1) {
            s_l += __shfl_down(s_l, o, 64);
            s_c += __shfl_down(s_c, o, 64);
            s_n += __shfl_down(s_n, o, 64);
        }
    }

    // block reduction across the 4 waves via LDS, then ONE plain store per block
    __shared__ float redc[4], redl[4], redcen[4];
    __shared__ int redn[4];
    const int wid = threadIdx.x >> 6;
    if ((threadIdx.x & 63) == 0) {
        redc[wid] = s_conf; redl[wid] = s_l; redcen[wid] = s_c; redn[wid] = s_n;
    }
    __syncthreads();
    if (threadIdx.x == 0) {
        float tc = (redc[0] + redc[1]) + (redc[2] + redc[3]);
        if (!is_box) {
            pc[((size_t)b * 8 + z) * GX + blockIdx.x] = tc;
        } else {
            pcor[b * GX + blockIdx.x] = tc;
            pl[b * GX + blockIdx.x]   = (redl[0] + redl[1]) + (redl[2] + redl[3]);
            pcen[b * GX + blockIdx.x] = (redcen[0] + redcen[1]) + (redcen[2] + redcen[3]);
            pn[b * GX + blockIdx.x]   = redn[0] + redn[1] + redn[2] + redn[3];
        }
    }
}

// One block, 1024 threads; wave b handles image b.
__global__ __launch_bounds__(1024) void fcos_final(const float* __restrict__ pc,
                                                   const float* __restrict__ pl,
                                                   const float* __restrict__ pcen,
                                                   const float* __restrict__ pcor,
                                                   const int* __restrict__ pn,
                                                   float* __restrict__ out) {
    const int tid  = threadIdx.x;
    const int b    = tid >> 6;
    const int lane = tid & 63;

    float sc = 0.f, sl = 0.f, scen = 0.f;
    int sn = 0;
    for (int i = lane; i < 8 * GX; i += 64) sc += pc[b * 8 * GX + i];
    if (lane < GX) {
        sc  += pcor[b * GX + lane];
        sl   = pl[b * GX + lane];
        scen = pcen[b * GX + lane];
        sn   = pn[b * GX + lane];
    }
    for (int o = 32; o > 0; o >>= 1) {
        sc   += __shfl_down(sc, o, 64);
        sl   += __shfl_down(sl, o, 64);
        scen += __shfl_down(scen, o, 64);
        sn   += __shfl_down(sn, o, 64);
    }

    __shared__ float vals[16];
    if (lane == 0) {
        float pf = fmaxf((float)sn, 1.f);
        vals[b] = (sn > 0) ? (scen + (sc + sl) / pf) : (scen + sc + sl);
    }
    __syncthreads();
    if (tid == 0) {
        float s = 0.f;
        for (int i = 0; i < 16; ++i) s += vals[i];
        out[0] = s * (1.f / 16.f);
    }
}

extern "C" void kernel_launch(void* const* d_in, const int* in_sizes, int n_in,
                              void* d_out, int out_size, void* d_ws, size_t ws_size,
                              hipStream_t stream) {
    LevelPtrs P;
    for (int l = 0; l < 5; ++l) {
        P.conf[l]   = (const float*)d_in[l * 6 + 0];
        P.loc[l]    = (const float*)d_in[l * 6 + 1];
        P.center[l] = (const float*)d_in[l * 6 + 2];
        P.ltrb[l]   = (const float*)d_in[l * 6 + 3];
        P.cls[l]    = (const int*)d_in[l * 6 + 4];
        P.pos[l]    = (const int*)d_in[l * 6 + 5];
    }
    float* pc   = (float*)d_ws;                 // 16*8*17 = 2176
    float* pl   = pc + 16 * 8 * GX;             // 272
    float* pcen = pl + 16 * GX;                 // 272
    float* pcor = pcen + 16 * GX;               // 272
    int*   pn   = (int*)(pcor + 16 * GX);       // 272

    dim3 grid(GX, 16, 9);  // z: 8 conf chunks + 1 box/correction slice
    fcos_main<<<grid, 256, 0, stream>>>(P, pc, pl, pcen, pcor, pn);
    fcos_final<<<1, 1024, 0, stream>>>(pc, pl, pcen, pcor, pn, (float*)d_out);
}

// Round 7
// 168.150 us; speedup vs baseline: 1.0237x; 1.0237x over previous
//
#include <hip/hip_runtime.h>

// FCOS loss, 5 FPN levels, B=16, C=80.
// Level pixel counts: 12800, 3200, 800, 208, 56 -> total 17064 (4266 quads).
// Two-stage deterministic reduction (no global atomics — R2/R3: same-line
// atomicAdds serialize to ~120us). R7 = R3 grid (8 z-slices, 8704 waves, one
// resident round) + R6 branch-free conf slices (cls/pos loaded only by z==0,
// which also does box losses + the positive-class focal correction).

namespace {
constexpr int NQUAD  = 4266;   // 17064 / 4
constexpr int C_     = 80;
constexpr int CCHUNK = 10;     // channels per conf block (8 chunks)
constexpr int GX     = 17;     // ceil(NQUAD/256)
constexpr float LN2  = 0.6931471805599453f;
constexpr float KNEG = -0.75f * LN2;   // -(1-alpha)*ln2
constexpr float KPOS = -0.25f * LN2;   // -alpha*ln2

struct LevelPtrs {
    const float* conf[5];
    const float* loc[5];
    const float* center[5];
    const float* ltrb[5];
    const int*   cls[5];
    const int*   pos[5];
};
}  // namespace

__device__ __forceinline__ float flog2(float x) { return __builtin_amdgcn_logf(x); }

__device__ __forceinline__ float neg_term(float v) {
    float p = fminf(fmaxf(v, 1e-8f), 0.99999999f);
    return KNEG * p * p * flog2(1.f - p);           // = -(0.75) p^2 ln(1-p)
}
__device__ __forceinline__ float pos_term(float v) {
    float p = fminf(fmaxf(v, 1e-8f), 0.99999999f);
    float om = 1.f - p;
    return KPOS * om * om * flog2(p);               // = -(0.25)(1-p)^2 ln(p)
}

__device__ __forceinline__ void level_of(int q, int& l, int& p, int& HW) {
    if (q < 3200)      { l = 0; p = 4 * q;          HW = 12800; }
    else if (q < 4000) { l = 1; p = 4 * (q - 3200); HW = 3200; }
    else if (q < 4200) { l = 2; p = 4 * (q - 4000); HW = 800; }
    else if (q < 4252) { l = 3; p = 4 * (q - 4200); HW = 208; }
    else               { l = 4; p = 4 * (q - 4252); HW = 56; }
}

// d_ws layout (floats):
//   pc  [16][8][17]  conf partial per (b, z, x)   : 2176   (z0 includes correction)
//   pl  [16][17]     iou partial per (b, x)       : 272
//   pcen[16][17]     centerness partial           : 272
//   pn  [16][17]     pos-count partial (int)      : 272
__global__ __launch_bounds__(256) void fcos_main(LevelPtrs P,
                                                 float* __restrict__ pc,
                                                 float* __restrict__ pl,
                                                 float* __restrict__ pcen,
                                                 int* __restrict__ pn) {
    const int b = blockIdx.y;
    const int z = blockIdx.z;           // 0..7 conf chunks; z==0 also box+corr
    const int q = blockIdx.x * 256 + threadIdx.x;
    const bool is_box = (z == 0);

    float s_conf = 0.f, s_l = 0.f, s_c = 0.f;
    int s_n = 0;

    if (q < NQUAD) {
        int l, p, HW;
        level_of(q, l, p, HW);
        const size_t bHW = (size_t)b * HW;

        // ---- branch-free focal negative stream over this chunk ----
        const int c0 = z * CCHUNK;
        const float* confp = P.conf[l] + ((size_t)b * C_ + c0) * HW + p;

        float4 vb[CCHUNK];
#pragma unroll
        for (int cc = 0; cc < CCHUNK; ++cc)
            vb[cc] = *(const float4*)(confp + (size_t)cc * HW);

        float4 sc = make_float4(0.f, 0.f, 0.f, 0.f);
#pragma unroll
        for (int cc = 0; cc < CCHUNK; ++cc) {
            sc.x += neg_term(vb[cc].x);
            sc.y += neg_term(vb[cc].y);
            sc.z += neg_term(vb[cc].z);
            sc.w += neg_term(vb[cc].w);
        }
        s_conf = (sc.x + sc.y) + (sc.z + sc.w);

        if (is_box) {
            // ---- box losses + positive-class conf correction (z==0 only) ----
            const int4 cls4 = *(const int4*)(P.cls[l] + bHW + p);
            const int4 pos4 = *(const int4*)(P.pos[l] + bHW + p);
            const int clsA[4] = {cls4.x, cls4.y, cls4.z, cls4.w};
            const int posA[4] = {pos4.x, pos4.y, pos4.z, pos4.w};
            const bool any = (posA[0] == 0) | (posA[1] == 0) |
                             (posA[2] == 0) | (posA[3] == 0);
            if (any) {
                const float* locp = P.loc[l]  + (size_t)b * 4 * HW + p;
                const float* ltrp = P.ltrb[l] + (size_t)b * 4 * HW + p;
                float la[4], ta[4], ra[4], ba[4];
                float La[4], Ta[4], Ra[4], Ba[4];
                float ca[4];
                *(float4*)la = *(const float4*)(locp);
                *(float4*)ta = *(const float4*)(locp + HW);
                *(float4*)ra = *(const float4*)(locp + 2 * HW);
                *(float4*)ba = *(const float4*)(locp + 3 * HW);
                *(float4*)La = *(const float4*)(ltrp);
                *(float4*)Ta = *(const float4*)(ltrp + HW);
                *(float4*)Ra = *(const float4*)(ltrp + 2 * HW);
                *(float4*)Ba = *(const float4*)(ltrp + 3 * HW);
                *(float4*)ca = *(const float4*)(P.center[l] + bHW + p);
#pragma unroll
                for (int i = 0; i < 4; ++i) {
                    if (posA[i] != 0) continue;
                    // focal correction at the labeled class (L2-hot line)
                    float v = P.conf[l][((size_t)b * C_ + clsA[i]) * HW + p + i];
                    s_conf += pos_term(v) - neg_term(v);

                    float lp = la[i] * 32.f, tp = ta[i] * 32.f,
                          rp = ra[i] * 32.f, bp = ba[i] * 32.f;
                    float lt = La[i] * 32.f, tt = Ta[i] * 32.f,
                          rt = Ra[i] * 32.f, bt = Ba[i] * 32.f;

                    float iw = fmaxf(fminf(lp, lt) + fminf(rp, rt), 0.f);
                    float ih = fmaxf(fminf(tp, tt) + fminf(bp, bt), 0.f);
                    float inter  = iw * ih;
                    float area_p = fmaxf(lp + rp, 0.f) * fmaxf(tp + bp, 0.f);
                    float area_t = (lt + rt) * (tt + bt);
                    float iou = inter / (area_p + area_t - inter + 1e-6f);
                    s_l += -LN2 * flog2(iou + 1e-6f);

                    float ctr = sqrtf((fminf(lt, rt) / (fmaxf(lt, rt) + 1e-6f)) *
                                      (fminf(tt, bt) / (fmaxf(tt, bt) + 1e-6f)));
                    float cp = fminf(fmaxf(ca[i], 1e-8f), 1.f - 1e-8f);
                    s_c += -LN2 * (ctr * flog2(cp) + (1.f - ctr) * flog2(1.f - cp));
                    s_n += 1;
                }
            }
        }
    }

    // wave64 shuffle reduction
    for (int o = 32; o > 0; o >>= 1) s_conf += __shfl_down(s_conf, o, 64);
    if (is_box) {
        for (int o = 32; o > 0; o >>= 1) {
            s_l += __shfl_down(s_l, o, 64);
            s_c += __shfl_down(s_c, o, 64);
            s_n += __shfl_down(s_n, o, 64);
        }
    }

    // block reduction across the 4 waves via LDS, then ONE plain store per block
    __shared__ float redc[4], redl[4], redcen[4];
    __shared__ int redn[4];
    const int wid = threadIdx.x >> 6;
    if ((threadIdx.x & 63) == 0) {
        redc[wid] = s_conf; redl[wid] = s_l; redcen[wid] = s_c; redn[wid] = s_n;
    }
    __syncthreads();
    if (threadIdx.x == 0) {
        pc[((size_t)b * 8 + z) * GX + blockIdx.x] =
            (redc[0] + redc[1]) + (redc[2] + redc[3]);
        if (is_box) {
            pl[b * GX + blockIdx.x]   = (redl[0] + redl[1]) + (redl[2] + redl[3]);
            pcen[b * GX + blockIdx.x] = (redcen[0] + redcen[1]) + (redcen[2] + redcen[3]);
            pn[b * GX + blockIdx.x]   = redn[0] + redn[1] + redn[2] + redn[3];
        }
    }
}

// One block, 1024 threads; wave b handles image b.
__global__ __launch_bounds__(1024) void fcos_final(const float* __restrict__ pc,
                                                   const float* __restrict__ pl,
                                                   const float* __restrict__ pcen,
                                                   const int* __restrict__ pn,
                                                   float* __restrict__ out) {
    const int tid  = threadIdx.x;
    const int b    = tid >> 6;
    const int lane = tid & 63;

    float sc = 0.f, sl = 0.f, scen = 0.f;
    int sn = 0;
    for (int i = lane; i < 8 * GX; i += 64) sc += pc[b * 8 * GX + i];
    if (lane < GX) {
        sl   = pl[b * GX + lane];
        scen = pcen[b * GX + lane];
        sn   = pn[b * GX + lane];
    }
    for (int o = 32; o > 0; o >>= 1) {
        sc   += __shfl_down(sc, o, 64);
        sl   += __shfl_down(sl, o, 64);
        scen += __shfl_down(scen, o, 64);
        sn   += __shfl_down(sn, o, 64);
    }

    __shared__ float vals[16];
    if (lane == 0) {
        float pf = fmaxf((float)sn, 1.f);
        vals[b] = (sn > 0) ? (scen + (sc + sl) / pf) : (scen + sc + sl);
    }
    __syncthreads();
    if (tid == 0) {
        float s = 0.f;
        for (int i = 0; i < 16; ++i) s += vals[i];
        out[0] = s * (1.f / 16.f);
    }
}

extern "C" void kernel_launch(void* const* d_in, const int* in_sizes, int n_in,
                              void* d_out, int out_size, void* d_ws, size_t ws_size,
                              hipStream_t stream) {
    LevelPtrs P;
    for (int l = 0; l < 5; ++l) {
        P.conf[l]   = (const float*)d_in[l * 6 + 0];
        P.loc[l]    = (const float*)d_in[l * 6 + 1];
        P.center[l] = (const float*)d_in[l * 6 + 2];
        P.ltrb[l]   = (const float*)d_in[l * 6 + 3];
        P.cls[l]    = (const int*)d_in[l * 6 + 4];
        P.pos[l]    = (const int*)d_in[l * 6 + 5];
    }
    float* pc   = (float*)d_ws;                 // 16*8*17 = 2176
    float* pl   = pc + 16 * 8 * GX;             // 272
    float* pcen = pl + 16 * GX;                 // 272
    int*   pn   = (int*)(pcen + 16 * GX);       // 272

    dim3 grid(GX, 16, 8);  // 8 z-slices; z==0 also does box + correction
    fcos_main<<<grid, 256, 0, stream>>>(P, pc, pl, pcen, pn);
    fcos_final<<<1, 1024, 0, stream>>>(pc, pl, pcen, pn, (float*)d_out);
}